// Round 12
// baseline (61.279 us; speedup 1.0000x reference)
//
#include <hip/hip_runtime.h>

typedef __bf16 bf16x8 __attribute__((ext_vector_type(8)));
typedef float f32x16 __attribute__((ext_vector_type(16)));
typedef unsigned u32x2 __attribute__((ext_vector_type(2)));

#define BB 2
#define HH 56
#define WW 56
#define NN 2
#define CC 128
#define NH 8
#define DD 16
#define WSP 7
#define LQ 784           // tokens per window = 56*7*2
#define KB_TOK 800       // K rows (zero-padded 784..799)
#define VT_STRIDE 808    // V^T token stride (bf16 elems)
#define NKC 25           // K chunks of 32
#define NINST 128        // 16 windows * 8 heads
#define BPI 5            // blocks per instance
#define NWAVE 5          // waves per block (1 Q-tile each)

// LDS layout (bytes): K [800][16] bf16 | V^T [16][808] bf16 | w [9][16] f32 | ones
#define K_OFF 0
#define V_OFF 25600
#define W_OFF 51456
#define ONES_OFF 52032
#define SMEM_BYTES 52064   // <= 53333 -> 3 blocks/CU

// scale * log2(e) so P = exp2(S) directly (no max-tracking; S bounded)
#define QSCALE 0.3606737602222409f

union U2 { __bf16 h[2]; unsigned u; };
union U4 { unsigned u[4]; bf16x8 v; };
union H8 { bf16x8 v; uint4 q; };

static __device__ __forceinline__ float4 f4zero() { float4 r; r.x = r.y = r.z = r.w = 0.f; return r; }
static __device__ __forceinline__ float4 f4add(float4 a, float4 b) {
    float4 r; r.x = a.x + b.x; r.y = a.y + b.y; r.z = a.z + b.z; r.w = a.w + b.w; return r;
}
static __device__ __forceinline__ float4 f4fmas(float4 acc, float4 w, float s, float4 S) {
    acc.x += w.x * s * S.x; acc.y += w.y * s * S.y; acc.z += w.z * s * S.z; acc.w += w.w * s * S.w; return acc;
}

// Single fused kernel: stage conv-w -> barrier -> RPE conv (front-loaded, in
// regs) + pack K/V to LDS -> barrier -> per-wave full-row flash attention with
// dual accumulators (2-chunk unroll) -> store out = rpe + attn (no RMW).
// Grid 640 = 128 inst * 5 parts, XCD-affine (inst&7 == bid&7).
__global__ __launch_bounds__(320) void attn_fused(const float* __restrict__ q_g,
                                                  const float* __restrict__ k_g,
                                                  const float* __restrict__ v_g,
                                                  const float* __restrict__ conv_w,
                                                  float* __restrict__ out) {
    __shared__ alignas(16) char smem[SMEM_BYTES];
    __bf16* Klds = (__bf16*)(smem + K_OFF);
    __bf16* Vlds = (__bf16*)(smem + V_OFF);
    float*  wlds = (float*)(smem + W_OFF);
    __bf16* onesb = (__bf16*)(smem + ONES_OFF);

    const int bid  = blockIdx.x;
    const int g    = bid >> 3;             // 0..79
    const int inst = (bid & 7) + 8 * (g / BPI);
    const int part = g % BPI;
    const int head = inst & 7;
    const int win  = inst >> 3;
    const int b    = win >> 3, wj = win & 7;
    const int tid  = threadIdx.x;

    // ---- stage conv weights transposed [k][16] + ones buffer ----
    if (tid < 144) {
        int c = tid & 15, k = tid >> 4;
        wlds[k * 16 + c] = conv_w[(head * 16 + c) * 9 + k];
    } else if (tid < 160) {
        onesb[tid - 144] = (__bf16)1.f;
    }
    __syncthreads();           // wlds ready (early barrier, waves arrive fast)

    // ---- per-lane geometry ----
    const int w    = tid >> 6;             // 0..4
    const int lane = tid & 63;
    const int col  = lane & 31;            // query col / key row / V^T row
    const int h    = lane >> 5;
    const int qt   = part * NWAVE + w;     // 0..24
    const int myq  = qt * 32 + col;
    const int sib  = myq ^ 1;

    const int myqc = myq < LQ ? myq : LQ - 1;
    const int pos = myqc >> 1, n = myqc & 1;
    const int y = pos / WSP, xl = pos - y * WSP;
    const long ooff = ((long)(((b * HH + y) * WW + wj * WSP + xl) * NN + n)) * CC + head * DD;

    // ---- RPE conv, front-loaded (independent load stream; overlaps pack) ----
    float4 cv0 = f4zero(), cv1 = f4zero();
    float4 sc0, sc1, vn0, vn1;
    {
        const int xg = wj * WSP + xl;
        const long rowbase = ((long)(b * HH + y) * WW + xg) * (NN * CC) + head * DD;
#pragma unroll
        for (int k = 0; k < 9; ++k) {
            int dy = k / 3 - 1, dx = k % 3 - 1;
            int yy = y + dy, xx = xg + dx;
            bool ok = (yy >= 0 && yy < HH && xx >= 0 && xx < WW);
            int yc = ok ? yy : y, xc = ok ? xx : xg;   // clamped (safe) address
            float m = ok ? 1.f : 0.f;
            const float* p = v_g + rowbase + ((long)(yc - y) * WW + (xc - xg)) * (NN * CC);
            float4 a0 = *(const float4*)(p + 4 * h);
            float4 b0 = *(const float4*)(p + CC + 4 * h);
            float4 a1 = *(const float4*)(p + 8 + 4 * h);
            float4 b1 = *(const float4*)(p + CC + 8 + 4 * h);
            float4 w0 = *(const float4*)(wlds + k * 16 + 4 * h);
            float4 w1 = *(const float4*)(wlds + k * 16 + 8 + 4 * h);
            float4 S0 = f4add(a0, b0);
            float4 S1 = f4add(a1, b1);
            cv0 = f4fmas(cv0, w0, m, S0);
            cv1 = f4fmas(cv1, w1, m, S1);
            if (k == 4) {
                sc0 = S0; sc1 = S1;
                vn0 = n ? b0 : a0;
                vn1 = n ? b1 : a1;
            }
        }
    }

    // ---- pack phase: f32 K/V -> bf16 LDS (fragment layout) ----
    for (int tok = tid; tok < KB_TOK; tok += 320) {
        if (tok < LQ) {
            int tpos = tok >> 1, tn = tok & 1;
            int ty = tpos / WSP, txl = tpos - ty * WSP;
            long off = ((long)(((b * HH + ty) * WW + wj * WSP + txl) * NN + tn)) * CC + head * DD;

            float kv[16], vv[16];
            *(float4*)&kv[0]  = *(const float4*)(k_g + off);
            *(float4*)&kv[4]  = *(const float4*)(k_g + off + 4);
            *(float4*)&kv[8]  = *(const float4*)(k_g + off + 8);
            *(float4*)&kv[12] = *(const float4*)(k_g + off + 12);
            *(float4*)&vv[0]  = *(const float4*)(v_g + off);
            *(float4*)&vv[4]  = *(const float4*)(v_g + off + 4);
            *(float4*)&vv[8]  = *(const float4*)(v_g + off + 8);
            *(float4*)&vv[12] = *(const float4*)(v_g + off + 12);

            H8 lo, hi;
#pragma unroll
            for (int i = 0; i < 8; ++i) { lo.v[i] = (__bf16)kv[i]; hi.v[i] = (__bf16)kv[8 + i]; }
            *(uint4*)&Klds[tok * 16]     = lo.q;
            *(uint4*)&Klds[tok * 16 + 8] = hi.q;
#pragma unroll
            for (int d = 0; d < 16; ++d)
                Vlds[d * VT_STRIDE + tok] = (__bf16)vv[d];
        } else {
            H8 z; z.q = make_uint4(0, 0, 0, 0);
            *(uint4*)&Klds[tok * 16]     = z.q;
            *(uint4*)&Klds[tok * 16 + 8] = z.q;
#pragma unroll
            for (int d = 0; d < 16; ++d)
                Vlds[d * VT_STRIDE + tok] = (__bf16)0.f;
        }
    }
    __syncthreads();

    // ---- attention: one full Q-tile per wave, dual-accumulator pipeline ----
    bf16x8 qfv;
    {
        const float* qp = q_g + ooff + 8 * h;
        float qv[8];
        *(float4*)&qv[0] = *(const float4*)qp;
        *(float4*)&qv[4] = *(const float4*)(qp + 4);
        H8 qq;
#pragma unroll
        for (int i = 0; i < 8; ++i) qq.v[i] = (__bf16)(qv[i] * QSCALE);
        qfv = qq.v;
    }

    f32x16 acc0, acc1, zv;
#pragma unroll
    for (int i = 0; i < 16; ++i) { acc0[i] = 0.f; acc1[i] = 0.f; zv[i] = 0.f; }

    const char* kbase = (const char*)Klds + col * 32 + h * 16;       // + c*1024
    const char* vbase;
    int vstep, tstep;
    if (col < 16) {
        vbase = (const char*)Vlds + col * (VT_STRIDE * 2) + h * 16;
        vstep = 64; tstep = 32;
    } else {
        vbase = (const char*)onesb;       // stride-0 ones broadcast (lsum)
        vstep = 0; tstep = 0;
    }

    auto do_chunk = [&](int c, f32x16& acc) {
        bf16x8 kf = *(const bf16x8*)(kbase + c * 1024);
        f32x16 st = __builtin_amdgcn_mfma_f32_32x32x16_bf16(kf, qfv, zv, 0, 0, 0);

        float p[16];
        if (c == qt || c == NKC - 1) {
#pragma unroll
            for (int r = 0; r < 16; ++r) {
                int kr = (r & 3) + 8 * (r >> 2) + 4 * h;
                int gk = c * 32 + kr;
                p[r] = (gk >= LQ || gk == sib) ? 0.f : __builtin_amdgcn_exp2f(st[r]);
            }
        } else {
#pragma unroll
            for (int r = 0; r < 16; ++r) p[r] = __builtin_amdgcn_exp2f(st[r]);
        }

        unsigned pk[4][2];
#pragma unroll
        for (int b2 = 0; b2 < 4; ++b2) {
            U2 a, bb;
            a.h[0]  = (__bf16)p[4 * b2 + 0];
            a.h[1]  = (__bf16)p[4 * b2 + 1];
            bb.h[0] = (__bf16)p[4 * b2 + 2];
            bb.h[1] = (__bf16)p[4 * b2 + 3];
            pk[b2][0] = a.u;
            pk[b2][1] = bb.u;
        }

#pragma unroll
        for (int t = 0; t < 2; ++t) {
            U4 pb;
#pragma unroll
            for (int j = 0; j < 2; ++j) {
#if __has_builtin(__builtin_amdgcn_permlane32_swap)
                u32x2 rr = __builtin_amdgcn_permlane32_swap(pk[2 * t][j], pk[2 * t + 1][j], false, false);
                pb.u[j]     = rr[0];
                pb.u[2 + j] = rr[1];
#else
                unsigned swa = __shfl_xor(pk[2 * t][j], 32, 64);
                unsigned swb = __shfl_xor(pk[2 * t + 1][j], 32, 64);
                pb.u[j]     = h ? swb : pk[2 * t][j];
                pb.u[2 + j] = h ? pk[2 * t + 1][j] : swa;
#endif
            }
            bf16x8 vf = *(const bf16x8*)(vbase + c * vstep + t * tstep);
            acc = __builtin_amdgcn_mfma_f32_32x32x16_bf16(vf, pb.v, acc, 0, 0, 0);
        }
    };

    for (int it = 0; it < 12; ++it) {     // 2 independent streams per iter
        do_chunk(2 * it, acc0);
        do_chunk(2 * it + 1, acc1);
    }
    do_chunk(24, acc0);                   // tail chunk

    // ---- store: out = rpe + attn (no RMW) ----
    if (myq < LQ) {
        float lsum = acc0[8] + acc1[8];   // ones-broadcast accumulators
        float inv = 1.f / lsum;
        float4 wc0 = *(const float4*)(wlds + 4 * 16 + 4 * h);
        float4 wc1 = *(const float4*)(wlds + 4 * 16 + 8 + 4 * h);
        float* po = out + ooff;
        float4 r0, r1;
        r0.x = cv0.x + wc0.x * (vn0.x - sc0.x) + (acc0[0] + acc1[0]) * inv;
        r0.y = cv0.y + wc0.y * (vn0.y - sc0.y) + (acc0[1] + acc1[1]) * inv;
        r0.z = cv0.z + wc0.z * (vn0.z - sc0.z) + (acc0[2] + acc1[2]) * inv;
        r0.w = cv0.w + wc0.w * (vn0.w - sc0.w) + (acc0[3] + acc1[3]) * inv;
        r1.x = cv1.x + wc1.x * (vn1.x - sc1.x) + (acc0[4] + acc1[4]) * inv;
        r1.y = cv1.y + wc1.y * (vn1.y - sc1.y) + (acc0[5] + acc1[5]) * inv;
        r1.z = cv1.z + wc1.z * (vn1.z - sc1.z) + (acc0[6] + acc1[6]) * inv;
        r1.w = cv1.w + wc1.w * (vn1.w - sc1.w) + (acc0[7] + acc1[7]) * inv;
        *(float4*)(po + 4 * h) = r0;
        *(float4*)(po + 8 + 4 * h) = r1;
    }
}

extern "C" void kernel_launch(void* const* d_in, const int* in_sizes, int n_in,
                              void* d_out, int out_size, void* d_ws, size_t ws_size,
                              hipStream_t stream) {
    const float* q = (const float*)d_in[0];
    const float* k = (const float*)d_in[1];
    const float* v = (const float*)d_in[2];
    const float* w = (const float*)d_in[3];
    float* out = (float*)d_out;

    attn_fused<<<NINST * BPI, 320, 0, stream>>>(q, k, v, w, out);
}

// Round 13
// 45.509 us; speedup vs baseline: 1.3465x; 1.3465x over previous
//
#include <hip/hip_runtime.h>

typedef __bf16 bf16x8 __attribute__((ext_vector_type(8)));
typedef float f32x16 __attribute__((ext_vector_type(16)));
typedef unsigned u32x2 __attribute__((ext_vector_type(2)));

#define BB 2
#define HH 56
#define WW 56
#define NN 2
#define CC 128
#define NH 8
#define DD 16
#define WSP 7
#define LQ 784           // tokens per window = 56*7*2
#define KB_TOK 800       // padded token count
#define VT_STRIDE 808    // V^T token stride (bf16 elems)
#define NKC 25           // K chunks of 32
#define NINST 128        // 16 windows * 8 heads
#define BPI 5            // blocks per instance
#define NTHR 640         // 10 waves: 5 Q-tiles x 2 K-halves

// LDS layout (bytes): V^T [16][808] bf16 | w [9][16] f32 | ones | red [5][64][10] f32
#define V_OFF 0
#define W_OFF 25856
#define ONES_OFF 26432
#define RED_OFF 26464
#define SMEM_BYTES 39264   // -> 4 blocks/CU by LDS; 3 by wave cap (30 waves/CU)

// scale * log2(e) so P = exp2(S) directly (no max-tracking; S bounded)
#define QSCALE 0.3606737602222409f

union U2 { __bf16 h[2]; unsigned u; };
union U4 { unsigned u[4]; bf16x8 v; };
union H8 { bf16x8 v; uint4 q; };

static __device__ __forceinline__ float4 f4zero() { float4 r; r.x = r.y = r.z = r.w = 0.f; return r; }
static __device__ __forceinline__ float4 f4add(float4 a, float4 b) {
    float4 r; r.x = a.x + b.x; r.y = a.y + b.y; r.z = a.z + b.z; r.w = a.w + b.w; return r;
}
static __device__ __forceinline__ float4 f4fma(float4 acc, float4 w, float4 s) {
    acc.x += w.x * s.x; acc.y += w.y * s.y; acc.z += w.z * s.z; acc.w += w.w * s.w; return acc;
}

// Single fused kernel, 2-way K-split: pack V^T to LDS -> each of 10 waves
// runs (Q-tile = part*5 + w/2, chunks c = (w&1), (w&1)+2, ...) with K
// fragments loaded+converted from global (L2-resident, XCD-affine grid).
// Halves combine via LDS; half-0 wave computes RPE conv in-register and
// stores out = rpe + attn (no RMW). Grid 640 = 128 inst * 5 parts.
__global__ __launch_bounds__(NTHR) void attn_fused(const float* __restrict__ q_g,
                                                   const float* __restrict__ k_g,
                                                   const float* __restrict__ v_g,
                                                   const float* __restrict__ conv_w,
                                                   float* __restrict__ out) {
    __shared__ alignas(16) char smem[SMEM_BYTES];
    __bf16* Vlds  = (__bf16*)(smem + V_OFF);
    float*  wlds  = (float*)(smem + W_OFF);
    __bf16* onesb = (__bf16*)(smem + ONES_OFF);
    float*  red   = (float*)(smem + RED_OFF);    // [5][64][10]

    const int bid  = blockIdx.x;
    const int g    = bid >> 3;             // 0..79
    const int inst = (bid & 7) + 8 * (g / BPI);
    const int part = g % BPI;
    const int head = inst & 7;
    const int win  = inst >> 3;
    const int b    = win >> 3, wj = win & 7;
    const int tid  = threadIdx.x;

    // ---- stage conv weights transposed [k][16] + ones buffer ----
    if (tid < 144) {
        int c = tid & 15, k = tid >> 4;
        wlds[k * 16 + c] = conv_w[(head * 16 + c) * 9 + k];
    } else if (tid < 160) {
        onesb[tid - 144] = (__bf16)1.f;
    }

    // ---- pack phase: f32 V -> bf16 V^T LDS ----
    for (int tok = tid; tok < KB_TOK; tok += NTHR) {
        if (tok < LQ) {
            int tpos = tok >> 1, tn = tok & 1;
            int ty = tpos / WSP, txl = tpos - ty * WSP;
            long off = ((long)(((b * HH + ty) * WW + wj * WSP + txl) * NN + tn)) * CC + head * DD;
            float vv[16];
            *(float4*)&vv[0]  = *(const float4*)(v_g + off);
            *(float4*)&vv[4]  = *(const float4*)(v_g + off + 4);
            *(float4*)&vv[8]  = *(const float4*)(v_g + off + 8);
            *(float4*)&vv[12] = *(const float4*)(v_g + off + 12);
#pragma unroll
            for (int d = 0; d < 16; ++d)
                Vlds[d * VT_STRIDE + tok] = (__bf16)vv[d];
        } else {
#pragma unroll
            for (int d = 0; d < 16; ++d)
                Vlds[d * VT_STRIDE + tok] = (__bf16)0.f;
        }
    }
    __syncthreads();

    // ---- per-wave geometry ----
    const int w     = tid >> 6;            // 0..9
    const int lane  = tid & 63;
    const int col   = lane & 31;           // query col / key row / V^T row
    const int h     = lane >> 5;
    const int tile  = w >> 1;              // 0..4
    const int khalf = w & 1;               // 0 or 1
    const int qt    = part * BPI + tile;   // 0..24
    const int myq   = qt * 32 + col;
    const int sib   = myq ^ 1;

    const int myqc = myq < LQ ? myq : LQ - 1;
    const int pos = myqc >> 1, n = myqc & 1;
    const int y = pos / WSP, xl = pos - y * WSP;
    const long ooff = ((long)(((b * HH + y) * WW + wj * WSP + xl) * NN + n)) * CC + head * DD;

    // Q fragment (B operand): col=query, k = d = 8h..8h+7; scale*log2e folded
    bf16x8 qfv;
    {
        const float* qp = q_g + ooff + 8 * h;
        float qv[8];
        *(float4*)&qv[0] = *(const float4*)qp;
        *(float4*)&qv[4] = *(const float4*)(qp + 4);
        H8 qq;
#pragma unroll
        for (int i = 0; i < 8; ++i) qq.v[i] = (__bf16)(qv[i] * QSCALE);
        qfv = qq.v;
    }

    f32x16 acc, zv;
#pragma unroll
    for (int i = 0; i < 16; ++i) { acc[i] = 0.f; zv[i] = 0.f; }

    const char* vbase;
    int vstep, tstep;
    if (col < 16) {
        vbase = (const char*)Vlds + col * (VT_STRIDE * 2) + h * 16;
        vstep = 64; tstep = 32;
    } else {
        vbase = (const char*)onesb;        // stride-0 ones broadcast (lsum)
        vstep = 0; tstep = 0;
    }

    for (int c = khalf; c < NKC; c += 2) {
        // K fragment from global (L2-resident): token c*32+col, dims 8h..8h+7
        bf16x8 kf;
        {
            int tok = c * 32 + col;
            int tokc = tok < LQ ? tok : LQ - 1;
            int tpos = tokc >> 1, tn = tokc & 1;
            int ty = tpos / WSP, txl = tpos - ty * WSP;
            long koff = ((long)(((b * HH + ty) * WW + wj * WSP + txl) * NN + tn)) * CC + head * DD + 8 * h;
            float kv[8];
            *(float4*)&kv[0] = *(const float4*)(k_g + koff);
            *(float4*)&kv[4] = *(const float4*)(k_g + koff + 4);
            H8 kk;
#pragma unroll
            for (int i = 0; i < 8; ++i) kk.v[i] = (__bf16)kv[i];
            kf = kk.v;
        }

        f32x16 st = __builtin_amdgcn_mfma_f32_32x32x16_bf16(kf, qfv, zv, 0, 0, 0);

        float p[16];
        if (c == qt || c == NKC - 1) {     // only these chunks need masking
#pragma unroll
            for (int r = 0; r < 16; ++r) {
                int kr = (r & 3) + 8 * (r >> 2) + 4 * h;
                int gk = c * 32 + kr;
                p[r] = (gk >= LQ || gk == sib) ? 0.f : __builtin_amdgcn_exp2f(st[r]);
            }
        } else {
#pragma unroll
            for (int r = 0; r < 16; ++r) p[r] = __builtin_amdgcn_exp2f(st[r]);
        }

        // pack P to bf16 pairs; pk[b2] covers keys 8*b2+4h..+3 of this chunk
        unsigned pk[4][2];
#pragma unroll
        for (int b2 = 0; b2 < 4; ++b2) {
            U2 a, bb;
            a.h[0]  = (__bf16)p[4 * b2 + 0];
            a.h[1]  = (__bf16)p[4 * b2 + 1];
            bb.h[0] = (__bf16)p[4 * b2 + 2];
            bb.h[1] = (__bf16)p[4 * b2 + 3];
            pk[b2][0] = a.u;
            pk[b2][1] = bb.u;
        }

#pragma unroll
        for (int t = 0; t < 2; ++t) {
            U4 pb;
#pragma unroll
            for (int j = 0; j < 2; ++j) {
#if __has_builtin(__builtin_amdgcn_permlane32_swap)
                u32x2 rr = __builtin_amdgcn_permlane32_swap(pk[2 * t][j], pk[2 * t + 1][j], false, false);
                pb.u[j]     = rr[0];
                pb.u[2 + j] = rr[1];
#else
                unsigned swa = __shfl_xor(pk[2 * t][j], 32, 64);
                unsigned swb = __shfl_xor(pk[2 * t + 1][j], 32, 64);
                pb.u[j]     = h ? swb : pk[2 * t][j];
                pb.u[2 + j] = h ? pk[2 * t + 1][j] : swa;
#endif
            }
            bf16x8 vf = *(const bf16x8*)(vbase + c * vstep + t * tstep);
            acc = __builtin_amdgcn_mfma_f32_32x32x16_bf16(vf, pb.v, acc, 0, 0, 0);
        }
    }

    // ---- combine the two K-halves via LDS ----
    if (khalf) {
        float* rp = red + (tile * 64 + lane) * 10;
#pragma unroll
        for (int i = 0; i < 9; ++i) rp[i] = acc[i];
    }
    __syncthreads();

    if (!khalf && myq < LQ) {
        const float* rp = red + (tile * 64 + lane) * 10;
        float o[9];
#pragma unroll
        for (int i = 0; i < 9; ++i) o[i] = acc[i] + rp[i];
        float inv = 1.f / o[8];            // lsum (ones broadcast row)

        // ---- in-register depthwise-conv RPE + write out (no RMW) ----
        const int xg = wj * WSP + xl;
        const long rowbase = ((long)(b * HH + y) * WW + xg) * (NN * CC) + head * DD;

        float4 cv0 = f4zero(), cv1 = f4zero();
        float4 sc0 = f4zero(), sc1 = f4zero();
        float4 vn0 = f4zero(), vn1 = f4zero();

#pragma unroll
        for (int dy = -1; dy <= 1; ++dy) {
            int yy = y + dy;
#pragma unroll
            for (int dx = -1; dx <= 1; ++dx) {
                int xx = xg + dx;
                if (yy < 0 || yy >= HH || xx < 0 || xx >= WW) continue;
                int k = (dy + 1) * 3 + (dx + 1);
                const float* p = v_g + rowbase + ((long)dy * WW + dx) * (NN * CC);
                float4 a0 = *(const float4*)(p + 4 * h);
                float4 b0 = *(const float4*)(p + CC + 4 * h);
                float4 a1 = *(const float4*)(p + 8 + 4 * h);
                float4 b1 = *(const float4*)(p + CC + 8 + 4 * h);
                float4 w0 = *(const float4*)(wlds + k * 16 + 4 * h);
                float4 w1 = *(const float4*)(wlds + k * 16 + 8 + 4 * h);
                float4 S0 = f4add(a0, b0);
                float4 S1 = f4add(a1, b1);
                cv0 = f4fma(cv0, w0, S0);
                cv1 = f4fma(cv1, w1, S1);
                if (dy == 0 && dx == 0) {
                    sc0 = S0; sc1 = S1;
                    vn0 = n ? b0 : a0;
                    vn1 = n ? b1 : a1;
                }
            }
        }
        float4 wc0 = *(const float4*)(wlds + 4 * 16 + 4 * h);
        float4 wc1 = *(const float4*)(wlds + 4 * 16 + 8 + 4 * h);

        float* po = out + ooff;
        float4 r0, r1;
        r0.x = cv0.x + wc0.x * (vn0.x - sc0.x) + o[0] * inv;
        r0.y = cv0.y + wc0.y * (vn0.y - sc0.y) + o[1] * inv;
        r0.z = cv0.z + wc0.z * (vn0.z - sc0.z) + o[2] * inv;
        r0.w = cv0.w + wc0.w * (vn0.w - sc0.w) + o[3] * inv;
        r1.x = cv1.x + wc1.x * (vn1.x - sc1.x) + o[4] * inv;
        r1.y = cv1.y + wc1.y * (vn1.y - sc1.y) + o[5] * inv;
        r1.z = cv1.z + wc1.z * (vn1.z - sc1.z) + o[6] * inv;
        r1.w = cv1.w + wc1.w * (vn1.w - sc1.w) + o[7] * inv;
        *(float4*)(po + 4 * h) = r0;
        *(float4*)(po + 8 + 4 * h) = r1;
    }
}

extern "C" void kernel_launch(void* const* d_in, const int* in_sizes, int n_in,
                              void* d_out, int out_size, void* d_ws, size_t ws_size,
                              hipStream_t stream) {
    const float* q = (const float*)d_in[0];
    const float* k = (const float*)d_in[1];
    const float* v = (const float*)d_in[2];
    const float* w = (const float*)d_in[3];
    float* out = (float*)d_out;

    attn_fused<<<NINST * BPI, NTHR, 0, stream>>>(q, k, v, w, out);
}

// Round 14
// 37.650 us; speedup vs baseline: 1.6276x; 1.2087x over previous
//
#include <hip/hip_runtime.h>

typedef __bf16 bf16x8 __attribute__((ext_vector_type(8)));
typedef float f32x16 __attribute__((ext_vector_type(16)));
typedef unsigned u32x2 __attribute__((ext_vector_type(2)));

#define BB 2
#define HH 56
#define WW 56
#define NN 2
#define CC 128
#define NH 8
#define DD 16
#define WSP 7
#define LQ 784           // tokens per window = 56*7*2
#define KB_TOK 800       // K rows (zero-padded 784..799)
#define VT_STRIDE 808    // V^T token stride (bf16 elems)
#define NKC 25           // K chunks of 32
#define NINST 128        // 16 windows * 8 heads
#define BPI 5            // blocks per instance
#define NWAVE 5          // waves per block (1 Q-tile each)

// LDS layout (bytes): K [800][16] bf16 (XOR-swizzled 16B units) | V^T [16][808]
// bf16 | w [9][16] f32 | ones
#define K_OFF 0
#define V_OFF 25600
#define W_OFF 51456
#define ONES_OFF 52032
#define SMEM_BYTES 52064

// scale * log2(e) so P = exp2(S) directly (no max-tracking; S bounded)
#define QSCALE 0.3606737602222409f

union U2 { __bf16 h[2]; unsigned u; };
union U4 { unsigned u[4]; bf16x8 v; };
union H8 { bf16x8 v; uint4 q; };

static __device__ __forceinline__ float4 f4zero() { float4 r; r.x = r.y = r.z = r.w = 0.f; return r; }
static __device__ __forceinline__ float4 f4add(float4 a, float4 b) {
    float4 r; r.x = a.x + b.x; r.y = a.y + b.y; r.z = a.z + b.z; r.w = a.w + b.w; return r;
}
static __device__ __forceinline__ float4 f4fma(float4 acc, float4 w, float4 s) {
    acc.x += w.x * s.x; acc.y += w.y * s.y; acc.z += w.z * s.z; acc.w += w.w * s.w; return acc;
}

// R11 structure + (1) XOR-swizzled K LDS (kills the 8-way bank conflict on
// every K ds_read_b128) + (2) dual accumulators (two independent per-chunk
// dependency streams). Grid 640 = 128 inst * 5 parts, XCD-affine.
__global__ __launch_bounds__(320) void attn_fused(const float* __restrict__ q_g,
                                                  const float* __restrict__ k_g,
                                                  const float* __restrict__ v_g,
                                                  const float* __restrict__ conv_w,
                                                  float* __restrict__ out) {
    __shared__ alignas(16) char smem[SMEM_BYTES];
    uint4*  K16   = (uint4*)(smem + K_OFF);      // 16B units, swizzled
    __bf16* Vlds  = (__bf16*)(smem + V_OFF);
    float*  wlds  = (float*)(smem + W_OFF);
    __bf16* onesb = (__bf16*)(smem + ONES_OFF);

    const int bid  = blockIdx.x;
    const int g    = bid >> 3;             // 0..79
    const int inst = (bid & 7) + 8 * (g / BPI);
    const int part = g % BPI;
    const int head = inst & 7;
    const int win  = inst >> 3;
    const int b    = win >> 3, wj = win & 7;
    const int tid  = threadIdx.x;

    // ---- stage conv weights transposed [k][16] + ones buffer ----
    if (tid < 144) {
        int c = tid & 15, k = tid >> 4;
        wlds[k * 16 + c] = conv_w[(head * 16 + c) * 9 + k];
    } else if (tid < 160) {
        onesb[tid - 144] = (__bf16)1.f;
    }

    // ---- pack phase: f32 K/V -> bf16 LDS (K swizzled, V^T transposed) ----
    for (int tok = tid; tok < KB_TOK; tok += 320) {
        if (tok < LQ) {
            int tpos = tok >> 1, tn = tok & 1;
            int ty = tpos / WSP, txl = tpos - ty * WSP;
            long off = ((long)(((b * HH + ty) * WW + wj * WSP + txl) * NN + tn)) * CC + head * DD;

            float kv[16], vv[16];
            *(float4*)&kv[0]  = *(const float4*)(k_g + off);
            *(float4*)&kv[4]  = *(const float4*)(k_g + off + 4);
            *(float4*)&kv[8]  = *(const float4*)(k_g + off + 8);
            *(float4*)&kv[12] = *(const float4*)(k_g + off + 12);
            *(float4*)&vv[0]  = *(const float4*)(v_g + off);
            *(float4*)&vv[4]  = *(const float4*)(v_g + off + 4);
            *(float4*)&vv[8]  = *(const float4*)(v_g + off + 8);
            *(float4*)&vv[12] = *(const float4*)(v_g + off + 12);

            H8 lo, hi;
#pragma unroll
            for (int i = 0; i < 8; ++i) { lo.v[i] = (__bf16)kv[i]; hi.v[i] = (__bf16)kv[8 + i]; }
            int sw = tok & 7;
            K16[(tok * 2)     ^ sw] = lo.q;
            K16[(tok * 2 + 1) ^ sw] = hi.q;
#pragma unroll
            for (int d = 0; d < 16; ++d)
                Vlds[d * VT_STRIDE + tok] = (__bf16)vv[d];
        } else {
            H8 z; z.q = make_uint4(0, 0, 0, 0);
            int sw = tok & 7;
            K16[(tok * 2)     ^ sw] = z.q;
            K16[(tok * 2 + 1) ^ sw] = z.q;
#pragma unroll
            for (int d = 0; d < 16; ++d)
                Vlds[d * VT_STRIDE + tok] = (__bf16)0.f;
        }
    }
    __syncthreads();

    // ---- per-wave geometry ----
    const int w    = tid >> 6;             // 0..4
    const int lane = tid & 63;
    const int col  = lane & 31;            // query col / key row / V^T row
    const int h    = lane >> 5;
    const int qt   = part * NWAVE + w;     // 0..24
    const int myq  = qt * 32 + col;
    const int sib  = myq ^ 1;

    const int myqc = myq < LQ ? myq : LQ - 1;
    const int pos = myqc >> 1, n = myqc & 1;
    const int y = pos / WSP, xl = pos - y * WSP;
    const long ooff = ((long)(((b * HH + y) * WW + wj * WSP + xl) * NN + n)) * CC + head * DD;

    // Q fragment (B operand): col=query, k = d = 8h..8h+7; scale*log2e folded
    bf16x8 qfv;
    {
        const float* qp = q_g + ooff + 8 * h;
        float qv[8];
        *(float4*)&qv[0] = *(const float4*)qp;
        *(float4*)&qv[4] = *(const float4*)(qp + 4);
        H8 qq;
#pragma unroll
        for (int i = 0; i < 8; ++i) qq.v[i] = (__bf16)(qv[i] * QSCALE);
        qfv = qq.v;
    }

    f32x16 acc0, acc1, zv;
#pragma unroll
    for (int i = 0; i < 16; ++i) { acc0[i] = 0.f; acc1[i] = 0.f; zv[i] = 0.f; }

    // swizzled K read base: tok = c*32+col -> idx16 = c*64 + col*2 + h, and
    // (c*64)&7 == 0, so the XOR folds into a constant lane base.
    const uint4* kbase = K16 + ((col * 2 + h) ^ (col & 7));   // + c*64
    const char* vbase;
    int vstep, tstep;
    if (col < 16) {
        vbase = (const char*)Vlds + col * (VT_STRIDE * 2) + h * 16;
        vstep = 64; tstep = 32;
    } else {
        vbase = (const char*)onesb;        // stride-0 ones broadcast (lsum)
        vstep = 0; tstep = 0;
    }

    auto do_chunk = [&](int c, f32x16& acc) {
        U4 kf; kf.u[0] = 0;
        *(uint4*)&kf = kbase[c * 64];
        f32x16 st = __builtin_amdgcn_mfma_f32_32x32x16_bf16(kf.v, qfv, zv, 0, 0, 0);

        float p[16];
        if (c == qt || c == NKC - 1) {
#pragma unroll
            for (int r = 0; r < 16; ++r) {
                int kr = (r & 3) + 8 * (r >> 2) + 4 * h;
                int gk = c * 32 + kr;
                p[r] = (gk >= LQ || gk == sib) ? 0.f : __builtin_amdgcn_exp2f(st[r]);
            }
        } else {
#pragma unroll
            for (int r = 0; r < 16; ++r) p[r] = __builtin_amdgcn_exp2f(st[r]);
        }

        unsigned pk[4][2];
#pragma unroll
        for (int b2 = 0; b2 < 4; ++b2) {
            U2 a, bb;
            a.h[0]  = (__bf16)p[4 * b2 + 0];
            a.h[1]  = (__bf16)p[4 * b2 + 1];
            bb.h[0] = (__bf16)p[4 * b2 + 2];
            bb.h[1] = (__bf16)p[4 * b2 + 3];
            pk[b2][0] = a.u;
            pk[b2][1] = bb.u;
        }

#pragma unroll
        for (int t = 0; t < 2; ++t) {
            U4 pb;
#pragma unroll
            for (int j = 0; j < 2; ++j) {
#if __has_builtin(__builtin_amdgcn_permlane32_swap)
                u32x2 rr = __builtin_amdgcn_permlane32_swap(pk[2 * t][j], pk[2 * t + 1][j], false, false);
                pb.u[j]     = rr[0];
                pb.u[2 + j] = rr[1];
#else
                unsigned swa = __shfl_xor(pk[2 * t][j], 32, 64);
                unsigned swb = __shfl_xor(pk[2 * t + 1][j], 32, 64);
                pb.u[j]     = h ? swb : pk[2 * t][j];
                pb.u[2 + j] = h ? pk[2 * t + 1][j] : swa;
#endif
            }
            bf16x8 vf = *(const bf16x8*)(vbase + c * vstep + t * tstep);
            acc = __builtin_amdgcn_mfma_f32_32x32x16_bf16(vf, pb.v, acc, 0, 0, 0);
        }
    };

    for (int it = 0; it < 12; ++it) {      // two independent streams
        do_chunk(2 * it, acc0);
        do_chunk(2 * it + 1, acc1);
    }
    do_chunk(24, acc0);

    // ---- epilogue: combine accs, in-register RPE conv, store (no RMW) ----
    if (myq < LQ) {
        float o[9];
#pragma unroll
        for (int i = 0; i < 9; ++i) o[i] = acc0[i] + acc1[i];
        float inv = 1.f / o[8];            // lsum (ones broadcast row)

        const int xg = wj * WSP + xl;
        const long rowbase = ((long)(b * HH + y) * WW + xg) * (NN * CC) + head * DD;

        float4 cv0 = f4zero(), cv1 = f4zero();
        float4 sc0 = f4zero(), sc1 = f4zero();
        float4 vn0 = f4zero(), vn1 = f4zero();

#pragma unroll
        for (int dy = -1; dy <= 1; ++dy) {
            int yy = y + dy;
#pragma unroll
            for (int dx = -1; dx <= 1; ++dx) {
                int xx = xg + dx;
                if (yy < 0 || yy >= HH || xx < 0 || xx >= WW) continue;
                int k = (dy + 1) * 3 + (dx + 1);
                const float* p = v_g + rowbase + ((long)dy * WW + dx) * (NN * CC);
                float4 a0 = *(const float4*)(p + 4 * h);
                float4 b0 = *(const float4*)(p + CC + 4 * h);
                float4 a1 = *(const float4*)(p + 8 + 4 * h);
                float4 b1 = *(const float4*)(p + CC + 8 + 4 * h);
                float4 w0 = *(const float4*)(wlds + k * 16 + 4 * h);
                float4 w1 = *(const float4*)(wlds + k * 16 + 8 + 4 * h);
                float4 S0 = f4add(a0, b0);
                float4 S1 = f4add(a1, b1);
                cv0 = f4fma(cv0, w0, S0);
                cv1 = f4fma(cv1, w1, S1);
                if (dy == 0 && dx == 0) {
                    sc0 = S0; sc1 = S1;
                    vn0 = n ? b0 : a0;
                    vn1 = n ? b1 : a1;
                }
            }
        }
        float4 wc0 = *(const float4*)(wlds + 4 * 16 + 4 * h);
        float4 wc1 = *(const float4*)(wlds + 4 * 16 + 8 + 4 * h);

        float* po = out + ooff;
        float4 r0, r1;
        r0.x = cv0.x + wc0.x * (vn0.x - sc0.x) + o[0] * inv;
        r0.y = cv0.y + wc0.y * (vn0.y - sc0.y) + o[1] * inv;
        r0.z = cv0.z + wc0.z * (vn0.z - sc0.z) + o[2] * inv;
        r0.w = cv0.w + wc0.w * (vn0.w - sc0.w) + o[3] * inv;
        r1.x = cv1.x + wc1.x * (vn1.x - sc1.x) + o[4] * inv;
        r1.y = cv1.y + wc1.y * (vn1.y - sc1.y) + o[5] * inv;
        r1.z = cv1.z + wc1.z * (vn1.z - sc1.z) + o[6] * inv;
        r1.w = cv1.w + wc1.w * (vn1.w - sc1.w) + o[7] * inv;
        *(float4*)(po + 4 * h) = r0;
        *(float4*)(po + 8 + 4 * h) = r1;
    }
}

extern "C" void kernel_launch(void* const* d_in, const int* in_sizes, int n_in,
                              void* d_out, int out_size, void* d_ws, size_t ws_size,
                              hipStream_t stream) {
    const float* q = (const float*)d_in[0];
    const float* k = (const float*)d_in[1];
    const float* v = (const float*)d_in[2];
    const float* w = (const float*)d_in[3];
    float* out = (float*)d_out;

    attn_fused<<<NINST * BPI, 320, 0, stream>>>(q, k, v, w, out);
}